// Round 12
// baseline (463.729 us; speedup 1.0000x reference)
//
#include <hip/hip_runtime.h>

typedef unsigned short ushort_t;
typedef ushort_t ushort8 __attribute__((ext_vector_type(8)));
typedef __bf16 bf16x8 __attribute__((ext_vector_type(8)));
typedef float f32x4 __attribute__((ext_vector_type(4)));
typedef float f32x16 __attribute__((ext_vector_type(16)));
typedef unsigned uint4v __attribute__((ext_vector_type(4)));

#define B_      16
#define QL_     32
#define H_      32
#define HKV_    8
#define D_      128
#define MAXSEQ_ 8192
#define REP_    4
#define ROWS_   128
#define KT_     64
#define NT_     256
#define KS_LD   136   // ushorts; 272B rows -> 4x bank spread on b128 reads
#define VT_LD   72    // ushorts; 144B rows (16B-mult for b128 reads)
#define NROWS_TOT (B_*HKV_*ROWS_)   // 16384
#define KVSTRIDE (HKV_*D_)          // floats between consecutive keys

__device__ __forceinline__ unsigned pkbf(float lo, float hi2) {
  unsigned a  = (unsigned)__builtin_bit_cast(ushort_t, (__bf16)lo);
  unsigned b2 = (unsigned)__builtin_bit_cast(ushort_t, (__bf16)hi2);
  return a | (b2 << 16);
}

// Flash attention, 32x32x16 MFMA. Block = (b, kv_head, split), 4 waves;
// wave w owns rep-head w. Swapped QK^T (C[key][q]); P rebuilt in registers
// via bf16-pack + v_permlane32_swap_b32. EXACT r5/r6 compute+staging (KT=64,
// verified correct twice; KT=32 branch abandoned -- unexplained 6.6e-2).
// r12: SINGLE-buffered LDS (35.8 KB) + __launch_bounds__(256,4) -> 4
// blocks/CU (VGPR=128 measured under a 256 cap in r7, so the cap is free);
// NSPLIT cascade 8/6/4 so the grid actually populates 4 blocks/CU.
template<int NSPLIT, bool DIRECT>
__global__ __launch_bounds__(NT_, 4)
void fa_main(const float* __restrict__ qg, const float* __restrict__ kg,
             const float* __restrict__ vg, const float* __restrict__ kcg,
             const float* __restrict__ vcg, const int* __restrict__ cslp,
             float* __restrict__ outg, float* __restrict__ opart,
             float* __restrict__ mpart, float* __restrict__ lpart)
{
  __shared__ __align__(16) ushort_t Ks[KT_ * KS_LD];   // K tile [key][d] bf16
  __shared__ __align__(16) ushort_t Vt[D_ * VT_LD];    // V tile transposed [d][key]

  const int t    = threadIdx.x;
  const int s    = (int)blockIdx.x % NSPLIT;
  const int bh   = (int)blockIdx.x / NSPLIT;
  const int b    = bh / HKV_;
  const int h    = bh % HKV_;
  const int cl   = cslp[0];            // cache_seq_len
  const int kvlen = cl + QL_;
  const int ntiles = (kvlen + KT_ - 1) / KT_;
  const int tps  = (ntiles + NSPLIT - 1) / NSPLIT;
  const int tt0  = s * tps;
  const int tt1  = min(ntiles, tt0 + tps);

  const int lane = t & 63;
  const int w    = t >> 6;        // wave 0..3 = rep-head index
  const int qcol = lane & 31;     // this lane's q (B-frag col / C col)
  const int hi   = lane >> 5;     // 0/1: k-half of fragments

  // ---- Q B-fragments, scale*log2e folded
  const float qscale = 0.088388347648318447f * 1.4426950408889634f;
  bf16x8 aQ[8];
  {
    const float* src = qg + (((size_t)b*QL_ + qcol)*H_ + h*REP_ + w)*D_ + hi*8;
    #pragma unroll
    for (int ks = 0; ks < 8; ++ks) {
      f32x4 v0 = *(const f32x4*)(src + ks*16);
      f32x4 v1 = *(const f32x4*)(src + ks*16 + 4);
      bf16x8 u;
      u[0]=(__bf16)(v0[0]*qscale); u[1]=(__bf16)(v0[1]*qscale);
      u[2]=(__bf16)(v0[2]*qscale); u[3]=(__bf16)(v0[3]*qscale);
      u[4]=(__bf16)(v1[0]*qscale); u[5]=(__bf16)(v1[1]*qscale);
      u[6]=(__bf16)(v1[2]*qscale); u[7]=(__bf16)(v1[3]*qscale);
      aQ[ks] = u;
    }
  }

  f32x16 oacc[4];                  // O[q][d], d-group db: col=d=db*32+qcol
  #pragma unroll
  for (int db = 0; db < 4; ++db)
    #pragma unroll
    for (int r = 0; r < 16; ++r) oacc[db][r] = 0.f;
  float m_run = -INFINITY;
  float l_run = 0.f;

  // staging thread->element maps (256 threads, 64-key tile)
  const int k_kl = t >> 2;           // K: key row 0..63
  const int k_d0 = (t & 3) * 32;     // K: 32 floats starting here
  const int v_k2 = (t & 31) * 2;     // V: 2 adjacent keys
  const int v_d0 = (t >> 5) * 16;    // V: 16 floats starting here

  const float* kc_base = kcg + (size_t)b*MAXSEQ_*KVSTRIDE + h*D_ + k_d0;
  const float* kn_base = kg  + (size_t)b*QL_*KVSTRIDE    + h*D_ + k_d0;
  const float* vc_base = vcg + (size_t)b*MAXSEQ_*KVSTRIDE + h*D_ + v_d0;
  const float* vn_base = vg  + (size_t)b*QL_*KVSTRIDE    + h*D_ + v_d0;

  f32x4 kr[8], vr[8];   // prefetch registers (held across compute phase)

  auto issue = [&](int tt) {
    const int p0 = tt * KT_;
    {
      int p = p0 + k_kl; if (p > kvlen - 1) p = kvlen - 1;
      const float* src = (p < cl) ? kc_base + (size_t)p*KVSTRIDE
                                  : kn_base + (size_t)(p - cl)*KVSTRIDE;
      #pragma unroll
      for (int j = 0; j < 8; ++j) kr[j] = *(const f32x4*)(src + 4*j);
    }
    #pragma unroll
    for (int kk = 0; kk < 2; ++kk) {
      int p = p0 + v_k2 + kk; if (p > kvlen - 1) p = kvlen - 1;
      const float* src = (p < cl) ? vc_base + (size_t)p*KVSTRIDE
                                  : vn_base + (size_t)(p - cl)*KVSTRIDE;
      #pragma unroll
      for (int j = 0; j < 4; ++j) vr[kk*4 + j] = *(const f32x4*)(src + 4*j);
    }
  };

  auto commit = [&]() {
    // K: 4x ds_write_b128
    #pragma unroll
    for (int c2 = 0; c2 < 4; ++c2) {
      ushort8 u;
      #pragma unroll
      for (int e = 0; e < 4; ++e) {
        u[e]   = __builtin_bit_cast(ushort_t, (__bf16)kr[c2*2][e]);
        u[4+e] = __builtin_bit_cast(ushort_t, (__bf16)kr[c2*2+1][e]);
      }
      *(ushort8*)&Ks[k_kl*KS_LD + k_d0 + c2*8] = u;
    }
    // V transposed: 16x ds_write_b32 (2 adjacent keys packed per dword)
    #pragma unroll
    for (int dj = 0; dj < 16; ++dj) {
      const unsigned pr = pkbf(vr[dj>>2][dj&3], vr[4 + (dj>>2)][dj&3]);
      *(unsigned*)&Vt[(v_d0 + dj)*VT_LD + v_k2] = pr;
    }
  };

  if (tt0 < tt1) { issue(tt0); commit(); }
  __syncthreads();

  for (int tt = tt0; tt < tt1; ++tt) {
    const bool hasNext = (tt + 1 < tt1);
    if (hasNext) issue(tt + 1);          // next-tile loads fly during compute

    const int p0 = tt * KT_;

    // ---- S^T = K Q^T : C[key][q], key-groups kg2 of 32
    f32x16 sacc[2];
    __builtin_amdgcn_s_setprio(1);
    #pragma unroll
    for (int kg2 = 0; kg2 < 2; ++kg2) {
      #pragma unroll
      for (int r = 0; r < 16; ++r) sacc[kg2][r] = 0.f;
      #pragma unroll
      for (int ks = 0; ks < 8; ++ks) {
        bf16x8 ak = __builtin_bit_cast(bf16x8,
            *(const ushort8*)&Ks[(kg2*32 + qcol)*KS_LD + ks*16 + hi*8]);
        sacc[kg2] = __builtin_amdgcn_mfma_f32_32x32x16_bf16(ak, aQ[ks], sacc[kg2], 0, 0, 0);
      }
    }
    __builtin_amdgcn_s_setprio(0);

    // ---- causal mask: key p visible to q iff p <= cl + q
    if (p0 + KT_ - 1 > cl) {
      #pragma unroll
      for (int kg2 = 0; kg2 < 2; ++kg2)
        #pragma unroll
        for (int r = 0; r < 16; ++r) {
          const int key = p0 + kg2*32 + (r&3) + 8*(r>>2) + 4*hi;
          if (key > cl + qcol) sacc[kg2][r] = -INFINITY;
        }
    }

    // ---- online softmax (log2 domain), in-register + 1 shfl_xor
    float tm = -INFINITY;
    #pragma unroll
    for (int kg2 = 0; kg2 < 2; ++kg2)
      #pragma unroll
      for (int r = 0; r < 16; ++r) tm = fmaxf(tm, sacc[kg2][r]);
    tm = fmaxf(tm, __shfl_xor(tm, 32, 64));

    if (__any(tm > m_run + 11.5f)) {     // defer-max (T13), 8*log2e
      const float mn    = fmaxf(m_run, tm);
      const float alpha = exp2f(m_run - mn);   // m_run=-inf -> 0
      m_run = mn;
      l_run *= alpha;
      #pragma unroll
      for (int r = 0; r < 16; ++r) {
        const int rq = (r&3) + 8*(r>>2) + 4*hi;
        const float ar = __shfl(alpha, rq, 64);
        #pragma unroll
        for (int db = 0; db < 4; ++db) oacc[db][r] *= ar;
      }
    }

    float rs = 0.f;
    #pragma unroll
    for (int kg2 = 0; kg2 < 2; ++kg2)
      #pragma unroll
      for (int r = 0; r < 16; ++r) {
        const float e = exp2f(sacc[kg2][r] - m_run);
        sacc[kg2][r] = e;
        rs += e;
      }
    rs += __shfl_xor(rs, 32, 64);
    l_run += rs;

    // ---- P -> A-frags in registers (pack + permlane32_swap), then PV
    #pragma unroll
    for (int kg2 = 0; kg2 < 2; ++kg2) {
      #pragma unroll
      for (int hl = 0; hl < 2; ++hl) {     // 16-key half
        const int rb = hl * 8;
        unsigned a0 = pkbf(sacc[kg2][rb+0], sacc[kg2][rb+1]);
        unsigned b0 = pkbf(sacc[kg2][rb+4], sacc[kg2][rb+5]);
        unsigned a1 = pkbf(sacc[kg2][rb+2], sacc[kg2][rb+3]);
        unsigned b1 = pkbf(sacc[kg2][rb+6], sacc[kg2][rb+7]);
        asm volatile("v_permlane32_swap_b32 %0, %1" : "+v"(a0), "+v"(b0));
        asm volatile("v_permlane32_swap_b32 %0, %1" : "+v"(a1), "+v"(b1));
        uint4v wv; wv[0] = a0; wv[1] = a1; wv[2] = b0; wv[3] = b1;
        const bf16x8 ap = __builtin_bit_cast(bf16x8, wv);
        const int kbase = kg2*32 + hl*16;
        __builtin_amdgcn_s_setprio(1);
        #pragma unroll
        for (int db = 0; db < 4; ++db) {
          bf16x8 bv = __builtin_bit_cast(bf16x8,
              *(const ushort8*)&Vt[(db*32 + qcol)*VT_LD + kbase + hi*8]);
          oacc[db] = __builtin_amdgcn_mfma_f32_32x32x16_bf16(ap, bv, oacc[db], 0, 0, 0);
        }
        __builtin_amdgcn_s_setprio(0);
      }
    }

    __syncthreads();            // readers done (drains prefetch vmcnt too)
    if (hasNext) commit();      // convert + LDS write for tile tt+1
    __syncthreads();            // writes visible
  }

  // ---- epilogue
  if constexpr (DIRECT) {
    const float inv_own = (l_run > 0.f) ? 1.f / l_run : 0.f;
    #pragma unroll
    for (int r = 0; r < 16; ++r) {
      const int rq = (r&3) + 8*(r>>2) + 4*hi;
      const float inv = __shfl(inv_own, rq, 64);
      float* dst = outg + (((size_t)b*QL_ + rq)*H_ + h*REP_ + w)*D_ + qcol;
      #pragma unroll
      for (int db = 0; db < 4; ++db) dst[db*32] = oacc[db][r] * inv;
    }
  } else {
    const int R0 = bh * ROWS_ + w * 32;
    #pragma unroll
    for (int r = 0; r < 16; ++r) {
      const int rq = (r&3) + 8*(r>>2) + 4*hi;
      float* dst = opart + ((size_t)s*NROWS_TOT + R0 + rq)*D_ + qcol;
      #pragma unroll
      for (int db = 0; db < 4; ++db) dst[db*32] = oacc[db][r];
    }
    if (lane < 32) {
      mpart[s*NROWS_TOT + R0 + lane] = m_run;
      lpart[s*NROWS_TOT + R0 + lane] = l_run;
    }
  }
}

// Combine NS partials: O = sum_s 2^(m_s-m*) O_s / sum_s 2^(m_s-m*) l_s
template<int NS>
__global__ void fa_combine(const float* __restrict__ opart,
                           const float* __restrict__ mpart,
                           const float* __restrict__ lpart,
                           float* __restrict__ outg)
{
  const int idx = (int)blockIdx.x * 256 + (int)threadIdx.x;
  const int R = idx >> 7;
  const int d = idx & 127;
  float mm = -INFINITY;
  #pragma unroll
  for (int si = 0; si < NS; ++si) mm = fmaxf(mm, mpart[si*NROWS_TOT + R]);
  float L = 0.f, o = 0.f;
  #pragma unroll
  for (int si = 0; si < NS; ++si) {
    const float ms = mpart[si*NROWS_TOT + R];
    const float wgt = (ms == -INFINITY) ? 0.f : exp2f(ms - mm);
    L += lpart[si*NROWS_TOT + R] * wgt;
    o += opart[((size_t)si*NROWS_TOT + R)*D_ + d] * wgt;
  }
  const float res = (L > 0.f) ? o / L : 0.f;
  const int b   = R >> 10;
  const int h   = (R >> 7) & 7;
  const int row = R & 127;
  outg[(((size_t)b*QL_ + (row & 31))*H_ + h*REP_ + (row >> 5))*D_ + d] = res;
}

template<int NS>
static void launch_split(const float* qg, const float* kg, const float* vg,
                         const float* kcg, const float* vcg, const int* csl,
                         float* outg, void* d_ws, hipStream_t stream)
{
  float* opart = (float*)d_ws;
  float* mpart = opart + (size_t)NS * NROWS_TOT * D_;
  float* lpart = mpart + (size_t)NS * NROWS_TOT;
  hipLaunchKernelGGL((fa_main<NS, false>), dim3(NS * B_ * HKV_), dim3(NT_), 0, stream,
                     qg, kg, vg, kcg, vcg, csl, nullptr, opart, mpart, lpart);
  hipLaunchKernelGGL((fa_combine<NS>), dim3(NROWS_TOT * D_ / 256), dim3(256), 0, stream,
                     opart, mpart, lpart, outg);
}

extern "C" void kernel_launch(void* const* d_in, const int* in_sizes, int n_in,
                              void* d_out, int out_size, void* d_ws, size_t ws_size,
                              hipStream_t stream)
{
  const float* qg  = (const float*)d_in[0];
  const float* kg  = (const float*)d_in[1];
  const float* vg  = (const float*)d_in[2];
  const float* kcg = (const float*)d_in[3];
  const float* vcg = (const float*)d_in[4];
  const int*   csl = (const int*)d_in[5];
  float* outg = (float*)d_out;

  auto need = [](int ns) {
    return (size_t)ns * NROWS_TOT * (D_ + 2) * sizeof(float);
  };
  if (ws_size >= need(8)) {        // ~68 MB: grid 1024 = 4 blocks/CU
    launch_split<8>(qg, kg, vg, kcg, vcg, csl, outg, d_ws, stream);
  } else if (ws_size >= need(6)) { // ~51 MB: grid 768 = 3 blocks/CU
    launch_split<6>(qg, kg, vg, kcg, vcg, csl, outg, d_ws, stream);
  } else if (ws_size >= need(4)) { // ~34 MB: r9-equivalent fallback
    launch_split<4>(qg, kg, vg, kcg, vcg, csl, outg, d_ws, stream);
  } else {
    hipLaunchKernelGGL((fa_main<1, true>), dim3(B_ * HKV_), dim3(NT_), 0, stream,
                       qg, kg, vg, kcg, vcg, csl, outg, nullptr, nullptr, nullptr);
  }
}

// Round 13
// 127.139 us; speedup vs baseline: 3.6474x; 3.6474x over previous
//
#include <hip/hip_runtime.h>

typedef unsigned short ushort_t;
typedef ushort_t ushort8 __attribute__((ext_vector_type(8)));
typedef __bf16 bf16x8 __attribute__((ext_vector_type(8)));
typedef float f32x4 __attribute__((ext_vector_type(4)));
typedef float f32x16 __attribute__((ext_vector_type(16)));
typedef unsigned uint4v __attribute__((ext_vector_type(4)));

#define B_      16
#define QL_     32
#define H_      32
#define HKV_    8
#define D_      128
#define MAXSEQ_ 8192
#define REP_    4
#define ROWS_   128
#define KT_     64
#define NT_     256
#define KS_LD   136   // ushorts; 272B rows -> 4x bank spread on b128 reads
#define VT_LD   72    // ushorts; 144B rows (16B-mult for b128 reads)
#define NROWS_TOT (B_*HKV_*ROWS_)   // 16384
#define KVSTRIDE (HKV_*D_)          // floats between consecutive keys

__device__ __forceinline__ unsigned pkbf(float lo, float hi2) {
  unsigned a  = (unsigned)__builtin_bit_cast(ushort_t, (__bf16)lo);
  unsigned b2 = (unsigned)__builtin_bit_cast(ushort_t, (__bf16)hi2);
  return a | (b2 << 16);
}

// Flash attention, 32x32x16 MFMA. Block = (b, kv_head, split), 4 waves;
// wave w owns rep-head w. Swapped QK^T (C[key][q]); P rebuilt in registers
// via bf16-pack + v_permlane32_swap_b32; double-buffered LDS, 1 barrier/tile.
// r13: EXACT r9/r6 body (verified, 129.6us) with NSPLIT=2 -- grid 512 is
// still exactly 2 blocks/CU (the register-true occupancy; (256,4) spilled in
// r12), but split/Q traffic halves vs NSPLIT=4 (~50 MB saved) and there is
// no second dispatch wave. XCD swizzle removed (measured neutral in r9).
template<int NSPLIT, bool DIRECT>
__global__ __launch_bounds__(NT_, 2)
void fa_main(const float* __restrict__ qg, const float* __restrict__ kg,
             const float* __restrict__ vg, const float* __restrict__ kcg,
             const float* __restrict__ vcg, const int* __restrict__ cslp,
             float* __restrict__ outg, float* __restrict__ opart,
             float* __restrict__ mpart, float* __restrict__ lpart)
{
  __shared__ __align__(16) ushort_t Ks[2][KT_ * KS_LD];   // K tiles [key][d] bf16
  __shared__ __align__(16) ushort_t Vt[2][D_ * VT_LD];    // V tiles transposed [d][key]

  const int t    = threadIdx.x;
  const int s    = (int)blockIdx.x % NSPLIT;
  const int bh   = (int)blockIdx.x / NSPLIT;
  const int b    = bh / HKV_;
  const int h    = bh % HKV_;
  const int cl   = cslp[0];            // cache_seq_len
  const int kvlen = cl + QL_;
  const int ntiles = (kvlen + KT_ - 1) / KT_;
  const int tps  = (ntiles + NSPLIT - 1) / NSPLIT;
  const int tt0  = s * tps;
  const int tt1  = min(ntiles, tt0 + tps);

  const int lane = t & 63;
  const int w    = t >> 6;        // wave 0..3 = rep-head index
  const int qcol = lane & 31;     // this lane's q (B-frag col / C col)
  const int hi   = lane >> 5;     // 0/1: k-half of fragments

  // ---- Q B-fragments, scale*log2e folded
  const float qscale = 0.088388347648318447f * 1.4426950408889634f;
  bf16x8 aQ[8];
  {
    const float* src = qg + (((size_t)b*QL_ + qcol)*H_ + h*REP_ + w)*D_ + hi*8;
    #pragma unroll
    for (int ks = 0; ks < 8; ++ks) {
      f32x4 v0 = *(const f32x4*)(src + ks*16);
      f32x4 v1 = *(const f32x4*)(src + ks*16 + 4);
      bf16x8 u;
      u[0]=(__bf16)(v0[0]*qscale); u[1]=(__bf16)(v0[1]*qscale);
      u[2]=(__bf16)(v0[2]*qscale); u[3]=(__bf16)(v0[3]*qscale);
      u[4]=(__bf16)(v1[0]*qscale); u[5]=(__bf16)(v1[1]*qscale);
      u[6]=(__bf16)(v1[2]*qscale); u[7]=(__bf16)(v1[3]*qscale);
      aQ[ks] = u;
    }
  }

  f32x16 oacc[4];                  // O[q][d], d-group db: col=d=db*32+qcol
  #pragma unroll
  for (int db = 0; db < 4; ++db)
    #pragma unroll
    for (int r = 0; r < 16; ++r) oacc[db][r] = 0.f;
  float m_run = -INFINITY;
  float l_run = 0.f;

  // staging thread->element maps (256 threads)
  const int k_kl = t >> 2;           // K: key row 0..63
  const int k_d0 = (t & 3) * 32;     // K: 32 floats starting here
  const int v_k2 = (t & 31) * 2;     // V: 2 adjacent keys
  const int v_d0 = (t >> 5) * 16;    // V: 16 floats starting here

  const float* kc_base = kcg + (size_t)b*MAXSEQ_*KVSTRIDE + h*D_ + k_d0;
  const float* kn_base = kg  + (size_t)b*QL_*KVSTRIDE    + h*D_ + k_d0;
  const float* vc_base = vcg + (size_t)b*MAXSEQ_*KVSTRIDE + h*D_ + v_d0;
  const float* vn_base = vg  + (size_t)b*QL_*KVSTRIDE    + h*D_ + v_d0;

  f32x4 kr[8], vr[8];   // prefetch registers (held across compute phase)

  auto issue = [&](int tt) {
    const int p0 = tt * KT_;
    {
      int p = p0 + k_kl; if (p > kvlen - 1) p = kvlen - 1;
      const float* src = (p < cl) ? kc_base + (size_t)p*KVSTRIDE
                                  : kn_base + (size_t)(p - cl)*KVSTRIDE;
      #pragma unroll
      for (int j = 0; j < 8; ++j) kr[j] = *(const f32x4*)(src + 4*j);
    }
    #pragma unroll
    for (int kk = 0; kk < 2; ++kk) {
      int p = p0 + v_k2 + kk; if (p > kvlen - 1) p = kvlen - 1;
      const float* src = (p < cl) ? vc_base + (size_t)p*KVSTRIDE
                                  : vn_base + (size_t)(p - cl)*KVSTRIDE;
      #pragma unroll
      for (int j = 0; j < 4; ++j) vr[kk*4 + j] = *(const f32x4*)(src + 4*j);
    }
  };

  auto commit = [&](int bufi) {
    #pragma unroll
    for (int c2 = 0; c2 < 4; ++c2) {
      ushort8 u;
      #pragma unroll
      for (int e = 0; e < 4; ++e) {
        u[e]   = __builtin_bit_cast(ushort_t, (__bf16)kr[c2*2][e]);
        u[4+e] = __builtin_bit_cast(ushort_t, (__bf16)kr[c2*2+1][e]);
      }
      *(ushort8*)&Ks[bufi][k_kl*KS_LD + k_d0 + c2*8] = u;
    }
    #pragma unroll
    for (int dj = 0; dj < 16; ++dj) {
      const unsigned pr = pkbf(vr[dj>>2][dj&3], vr[4 + (dj>>2)][dj&3]);
      *(unsigned*)&Vt[bufi][(v_d0 + dj)*VT_LD + v_k2] = pr;
    }
  };

  if (tt0 < tt1) { issue(tt0); commit(0); }
  __syncthreads();

  for (int tt = tt0; tt < tt1; ++tt) {
    const int  cur     = (tt - tt0) & 1;
    const bool hasNext = (tt + 1 < tt1);
    if (hasNext) issue(tt + 1);          // next-tile loads fly during compute

    const int p0 = tt * KT_;

    // ---- S^T = K Q^T : C[key][q]
    f32x16 sacc[2];
    __builtin_amdgcn_s_setprio(1);
    #pragma unroll
    for (int kg2 = 0; kg2 < 2; ++kg2) {
      #pragma unroll
      for (int r = 0; r < 16; ++r) sacc[kg2][r] = 0.f;
      #pragma unroll
      for (int ks = 0; ks < 8; ++ks) {
        bf16x8 ak = __builtin_bit_cast(bf16x8,
            *(const ushort8*)&Ks[cur][(kg2*32 + qcol)*KS_LD + ks*16 + hi*8]);
        sacc[kg2] = __builtin_amdgcn_mfma_f32_32x32x16_bf16(ak, aQ[ks], sacc[kg2], 0, 0, 0);
      }
    }
    __builtin_amdgcn_s_setprio(0);

    // ---- causal mask: key p visible to q iff p <= cl + q
    if (p0 + KT_ - 1 > cl) {
      #pragma unroll
      for (int kg2 = 0; kg2 < 2; ++kg2)
        #pragma unroll
        for (int r = 0; r < 16; ++r) {
          const int key = p0 + kg2*32 + (r&3) + 8*(r>>2) + 4*hi;
          if (key > cl + qcol) sacc[kg2][r] = -INFINITY;
        }
    }

    // ---- online softmax (log2 domain), in-register + 1 shfl_xor
    float tm = -INFINITY;
    #pragma unroll
    for (int kg2 = 0; kg2 < 2; ++kg2)
      #pragma unroll
      for (int r = 0; r < 16; ++r) tm = fmaxf(tm, sacc[kg2][r]);
    tm = fmaxf(tm, __shfl_xor(tm, 32, 64));

    if (__any(tm > m_run + 11.5f)) {     // defer-max (T13), 8*log2e
      const float mn    = fmaxf(m_run, tm);
      const float alpha = exp2f(m_run - mn);   // m_run=-inf -> 0
      m_run = mn;
      l_run *= alpha;
      #pragma unroll
      for (int r = 0; r < 16; ++r) {
        const int rq = (r&3) + 8*(r>>2) + 4*hi;
        const float ar = __shfl(alpha, rq, 64);
        #pragma unroll
        for (int db = 0; db < 4; ++db) oacc[db][r] *= ar;
      }
    }

    float rs = 0.f;
    #pragma unroll
    for (int kg2 = 0; kg2 < 2; ++kg2)
      #pragma unroll
      for (int r = 0; r < 16; ++r) {
        const float e = exp2f(sacc[kg2][r] - m_run);
        sacc[kg2][r] = e;
        rs += e;
      }
    rs += __shfl_xor(rs, 32, 64);
    l_run += rs;

    // ---- P -> A-frags in registers (pack + permlane32_swap), then PV
    #pragma unroll
    for (int kg2 = 0; kg2 < 2; ++kg2) {
      #pragma unroll
      for (int hl = 0; hl < 2; ++hl) {     // 16-key half
        const int rb = hl * 8;
        unsigned a0 = pkbf(sacc[kg2][rb+0], sacc[kg2][rb+1]);
        unsigned b0 = pkbf(sacc[kg2][rb+4], sacc[kg2][rb+5]);
        unsigned a1 = pkbf(sacc[kg2][rb+2], sacc[kg2][rb+3]);
        unsigned b1 = pkbf(sacc[kg2][rb+6], sacc[kg2][rb+7]);
        asm volatile("v_permlane32_swap_b32 %0, %1" : "+v"(a0), "+v"(b0));
        asm volatile("v_permlane32_swap_b32 %0, %1" : "+v"(a1), "+v"(b1));
        uint4v wv; wv[0] = a0; wv[1] = a1; wv[2] = b0; wv[3] = b1;
        const bf16x8 ap = __builtin_bit_cast(bf16x8, wv);
        const int kbase = kg2*32 + hl*16;
        __builtin_amdgcn_s_setprio(1);
        #pragma unroll
        for (int db = 0; db < 4; ++db) {
          bf16x8 bv = __builtin_bit_cast(bf16x8,
              *(const ushort8*)&Vt[cur][(db*32 + qcol)*VT_LD + kbase + hi*8]);
          oacc[db] = __builtin_amdgcn_mfma_f32_32x32x16_bf16(ap, bv, oacc[db], 0, 0, 0);
        }
        __builtin_amdgcn_s_setprio(0);
      }
    }

    if (hasNext) commit(cur ^ 1);   // other buffer; last readers pre-prev-barrier
    __syncthreads();
  }

  // ---- epilogue
  if constexpr (DIRECT) {
    const float inv_own = (l_run > 0.f) ? 1.f / l_run : 0.f;
    #pragma unroll
    for (int r = 0; r < 16; ++r) {
      const int rq = (r&3) + 8*(r>>2) + 4*hi;
      const float inv = __shfl(inv_own, rq, 64);
      float* dst = outg + (((size_t)b*QL_ + rq)*H_ + h*REP_ + w)*D_ + qcol;
      #pragma unroll
      for (int db = 0; db < 4; ++db) dst[db*32] = oacc[db][r] * inv;
    }
  } else {
    const int R0 = bh * ROWS_ + w * 32;
    #pragma unroll
    for (int r = 0; r < 16; ++r) {
      const int rq = (r&3) + 8*(r>>2) + 4*hi;
      float* dst = opart + ((size_t)s*NROWS_TOT + R0 + rq)*D_ + qcol;
      #pragma unroll
      for (int db = 0; db < 4; ++db) dst[db*32] = oacc[db][r];
    }
    if (lane < 32) {
      mpart[s*NROWS_TOT + R0 + lane] = m_run;
      lpart[s*NROWS_TOT + R0 + lane] = l_run;
    }
  }
}

// Combine NS partials: O = sum_s 2^(m_s-m*) O_s / sum_s 2^(m_s-m*) l_s
template<int NS>
__global__ void fa_combine(const float* __restrict__ opart,
                           const float* __restrict__ mpart,
                           const float* __restrict__ lpart,
                           float* __restrict__ outg)
{
  const int idx = (int)blockIdx.x * 256 + (int)threadIdx.x;
  const int R = idx >> 7;
  const int d = idx & 127;
  float mm = -INFINITY;
  #pragma unroll
  for (int si = 0; si < NS; ++si) mm = fmaxf(mm, mpart[si*NROWS_TOT + R]);
  float L = 0.f, o = 0.f;
  #pragma unroll
  for (int si = 0; si < NS; ++si) {
    const float ms = mpart[si*NROWS_TOT + R];
    const float wgt = (ms == -INFINITY) ? 0.f : exp2f(ms - mm);
    L += lpart[si*NROWS_TOT + R] * wgt;
    o += opart[((size_t)si*NROWS_TOT + R)*D_ + d] * wgt;
  }
  const float res = (L > 0.f) ? o / L : 0.f;
  const int b   = R >> 10;
  const int h   = (R >> 7) & 7;
  const int row = R & 127;
  outg[(((size_t)b*QL_ + (row & 31))*H_ + h*REP_ + (row >> 5))*D_ + d] = res;
}

extern "C" void kernel_launch(void* const* d_in, const int* in_sizes, int n_in,
                              void* d_out, int out_size, void* d_ws, size_t ws_size,
                              hipStream_t stream)
{
  const float* qg  = (const float*)d_in[0];
  const float* kg  = (const float*)d_in[1];
  const float* vg  = (const float*)d_in[2];
  const float* kcg = (const float*)d_in[3];
  const float* vcg = (const float*)d_in[4];
  const int*   csl = (const int*)d_in[5];
  float* outg = (float*)d_out;

  const size_t need2 = (size_t)2 * NROWS_TOT * (D_ + 2) * sizeof(float); // ~17 MB
  if (ws_size >= need2) {
    float* opart = (float*)d_ws;
    float* mpart = opart + (size_t)2 * NROWS_TOT * D_;
    float* lpart = mpart + 2 * NROWS_TOT;
    hipLaunchKernelGGL((fa_main<2, false>), dim3(2 * B_ * HKV_), dim3(NT_), 0, stream,
                       qg, kg, vg, kcg, vcg, csl, nullptr, opart, mpart, lpart);
    hipLaunchKernelGGL((fa_combine<2>), dim3(NROWS_TOT * D_ / 256), dim3(256), 0, stream,
                       opart, mpart, lpart, outg);
  } else {
    hipLaunchKernelGGL((fa_main<1, true>), dim3(B_ * HKV_), dim3(NT_), 0, stream,
                       qg, kg, vg, kcg, vcg, csl, outg, nullptr, nullptr, nullptr);
  }
}